// Round 14
// baseline (202.913 us; speedup 1.0000x reference)
//
#include <hip/hip_runtime.h>

// Cross_AttentionHead_withMask: B=8, TQ=2048, TK=4096, DIM_IMG=512, DIM_TXT=128, HS=64
// bf16 MFMA; no online-max (|wei| <~ 3) => num/den linear => TK split + exact reduce.
// ws: K bf16 [8][4096][64] | Vt bf16 [8][64][4096] | Q bf16 [8][2048][64] (10 MB)
//     num f32 [8][8][2048][64] (32 MB) | den f32 [8][8][2048] (512 KB)
// r12/r13 profile: harness ws-poison + d_in restore = fixed ~65 us floor in dur_us.
// r13 change: V is NOT LDS-staged (m169 precedent: batch V = 0.5 MB, L2-resident via
// bid&7 XCD affinity) -> LDS 70.6->53.2 KB -> 3 blocks/CU; NSPL=8 fills the capacity.

#define B_    8
#define TQ_   2048
#define TK_   4096
#define DIMG  512
#define DTXT  128
#define HS_   64
#define NSPL  8
#define TSPL  (TK_ / NSPL)   // 512

typedef float f32x4 __attribute__((ext_vector_type(4)));
typedef __bf16 bf16x8 __attribute__((ext_vector_type(8)));

// native RNE f32->bf16 (compiler emits v_cvt_pk_bf16_f32 for pairs)
static __device__ __forceinline__ unsigned short f2bf(float x) {
    __bf16 b = (__bf16)x;
    return __builtin_bit_cast(unsigned short, b);
}
static __device__ __forceinline__ unsigned pk2(float a, float b) {
    return (unsigned)f2bf(a) | ((unsigned)f2bf(b) << 16);
}

// ---- fused projections: blocks 0..511 = K/V (double-buffered), 512..767 = Q ----
#define STAGE_KV(XBUF, WBUF, kc)                                                      \
    {                                                                                 \
        _Pragma("unroll")                                                             \
        for (int m = 0; m < 4; ++m) {                                                 \
            int lin = tid + 256 * m;                                                  \
            int r = lin >> 4;                                                         \
            int c = (lin & 15) * 4;                                                   \
            float4 v = *(const float4*)(x_image + ((size_t)(b * TK_ + t0 + r)) * DIMG + (kc) + c); \
            *(uint2*)&XBUF[r][c] = make_uint2(pk2(v.x, v.y), pk2(v.z, v.w));          \
        }                                                                             \
        _Pragma("unroll")                                                             \
        for (int m = 0; m < 8; ++m) {                                                 \
            int lin = tid + 256 * m;                                                  \
            int r = lin >> 4;                                                         \
            int c = (lin & 15) * 4;                                                   \
            const float* src = (r < 64) ? (Wk + (size_t)r * DIMG + (kc) + c)          \
                                        : (Wv + (size_t)(r - 64) * DIMG + (kc) + c);  \
            float4 v = *(const float4*)src;                                           \
            *(uint2*)&WBUF[r][c] = make_uint2(pk2(v.x, v.y), pk2(v.z, v.w));          \
        }                                                                             \
    }

#define COMPUTE_KV(XBUF, WBUF)                                                        \
    {                                                                                 \
        bf16x8 a0 = *(const bf16x8*)&XBUF[16 * w + col][hi4 * 8];                     \
        bf16x8 a1 = *(const bf16x8*)&XBUF[16 * w + col][hi4 * 8 + 32];                \
        _Pragma("unroll")                                                             \
        for (int g = 0; g < 8; ++g) {                                                 \
            bf16x8 b0 = *(const bf16x8*)&WBUF[g * 16 + col][hi4 * 8];                 \
            bf16x8 b1 = *(const bf16x8*)&WBUF[g * 16 + col][hi4 * 8 + 32];            \
            acc[g] = __builtin_amdgcn_mfma_f32_16x16x32_bf16(a0, b0, acc[g], 0, 0, 0);\
            acc[g] = __builtin_amdgcn_mfma_f32_16x16x32_bf16(a1, b1, acc[g], 0, 0, 0);\
        }                                                                             \
    }

__global__ __launch_bounds__(256) void proj_fused_kernel(
    const float* __restrict__ x_image, const float* __restrict__ fx,
    const float* __restrict__ fy, const float* __restrict__ Wk,
    const float* __restrict__ Wv, const float* __restrict__ x_text,
    const float* __restrict__ fl, const float* __restrict__ Wq,
    unsigned short* __restrict__ K_ws, unsigned short* __restrict__ Vt_ws,
    unsigned short* __restrict__ Q_ws)
{
    __shared__ __align__(16) unsigned short lds[27648];   // 55.3 KB union

    const int tid = threadIdx.x;
    const int bid = blockIdx.x;
    const int w  = tid >> 6;
    const int l  = tid & 63;
    const int col = l & 15;
    const int hi4 = l >> 4;

    if (bid < 512) {
        // ---------------- K/V path: 64 tokens, double-buffered k-chunks ----------
        auto Xc0 = (unsigned short(*)[72])(lds);
        auto Xc1 = (unsigned short(*)[72])(lds + 4608);
        auto Wc0 = (unsigned short(*)[72])(lds + 9216);
        auto Wc1 = (unsigned short(*)[72])(lds + 18432);

        const int b  = bid & 7;
        const int t0 = (bid >> 3) * 64;

        f32x4 acc[8];
        #pragma unroll
        for (int g = 0; g < 8; ++g) acc[g] = (f32x4){0.f, 0.f, 0.f, 0.f};

        STAGE_KV(Xc0, Wc0, 0);
        __syncthreads();
        for (int c2 = 0; c2 < 8; c2 += 2) {
            STAGE_KV(Xc1, Wc1, (c2 + 1) * 64);      // next chunk flies under MFMA
            COMPUTE_KV(Xc0, Wc0);
            __syncthreads();
            if (c2 + 2 < 8) STAGE_KV(Xc0, Wc0, (c2 + 2) * 64);
            COMPUTE_KV(Xc1, Wc1);
            __syncthreads();
        }

        const int rbase = hi4 * 4;
        #pragma unroll
        for (int g = 0; g < 4; ++g) {          // K heads: RoPE 2D, store [b][t][h]
            int h = g * 16 + col;
            const float* ftab = (h < 32) ? fx : fy;
            int i = (h & 31) >> 1;
            float sgn = (h & 1) ? 1.f : -1.f;
            #pragma unroll
            for (int j = 0; j < 4; ++j) {
                int t = t0 + 16 * w + rbase + j;
                float v = acc[g][j];
                float p = __shfl_xor(v, 1);
                float2 cs = *(const float2*)(ftab + ((size_t)t * 16 + i) * 2);
                float o = v * cs.x + sgn * p * cs.y;
                K_ws[((size_t)(b * TK_ + t)) * HS_ + h] = f2bf(o);
            }
        }
        #pragma unroll
        for (int g = 4; g < 8; ++g) {          // V heads: store transposed [b][h][t]
            int h = (g - 4) * 16 + col;
            int tb = t0 + 16 * w + rbase;
            *(uint2*)&Vt_ws[((size_t)(b * HS_ + h)) * TK_ + tb] =
                make_uint2(pk2(acc[g][0], acc[g][1]), pk2(acc[g][2], acc[g][3]));
        }
    } else {
        // ---------------- Q path: stage all 128 dims once, 1 barrier -------------
        auto Xq = (unsigned short(*)[136])(lds);
        auto Wl = (unsigned short(*)[136])(lds + 8704);

        const int b  = bid & 7;
        const int s0 = ((bid - 512) >> 3) * 64;

        #pragma unroll
        for (int m = 0; m < 8; ++m) {
            int lin = tid + 256 * m;
            int r = lin >> 5;
            int c = (lin & 31) * 4;
            float4 v = *(const float4*)(x_text + ((size_t)(b * TQ_ + s0 + r)) * DTXT + c);
            *(uint2*)&Xq[r][c] = make_uint2(pk2(v.x, v.y), pk2(v.z, v.w));
        }
        #pragma unroll
        for (int m = 0; m < 8; ++m) {
            int lin = tid + 256 * m;
            int r = lin >> 5;
            int c = (lin & 31) * 4;
            float4 v = *(const float4*)(Wq + (size_t)r * DTXT + c);
            *(uint2*)&Wl[r][c] = make_uint2(pk2(v.x, v.y), pk2(v.z, v.w));
        }
        __syncthreads();

        f32x4 acc[4];
        #pragma unroll
        for (int g = 0; g < 4; ++g) acc[g] = (f32x4){0.f, 0.f, 0.f, 0.f};
        #pragma unroll
        for (int kk = 0; kk < 4; ++kk) {
            bf16x8 a = *(const bf16x8*)&Xq[16 * w + col][hi4 * 8 + kk * 32];
            #pragma unroll
            for (int g = 0; g < 4; ++g) {
                bf16x8 bb = *(const bf16x8*)&Wl[g * 16 + col][hi4 * 8 + kk * 32];
                acc[g] = __builtin_amdgcn_mfma_f32_16x16x32_bf16(a, bb, acc[g], 0, 0, 0);
            }
        }

        const float SCALE = 0.044194173824159216f;   // 1/sqrt(512)
        const int rbase = hi4 * 4;
        #pragma unroll
        for (int g = 0; g < 4; ++g) {
            int h = g * 16 + col;
            int i = h >> 1;
            float sgn = (h & 1) ? 1.f : -1.f;
            #pragma unroll
            for (int j = 0; j < 4; ++j) {
                int s = s0 + 16 * w + rbase + j;
                float v = acc[g][j];
                float p = __shfl_xor(v, 1);
                float2 cs = *(const float2*)(fl + ((size_t)s * 32 + i) * 2);
                float o = (v * cs.x + sgn * p * cs.y) * SCALE;
                Q_ws[((size_t)(b * TQ_ + s)) * HS_ + h] = f2bf(o);
            }
        }
    }
}

// --- split attention: K staged (T14 prefetch), V read direct from L2, no Vv LDS ---
// LDS = Kt 18432 + Pl 34816 = 53248 B -> 3 blocks/CU; grid 1024 fills it.
__global__ __launch_bounds__(512, 6) void attn_partial_kernel(
    const unsigned short* __restrict__ Q_ws,
    const unsigned short* __restrict__ K_ws,
    const unsigned short* __restrict__ Vt_ws,
    float* __restrict__ num_ws, float* __restrict__ den_ws)
{
    __shared__ unsigned short Kt[128][72];       // t-tile x heads (padded)
    __shared__ unsigned short Pl[8][16][136];    // per-wave P redistribution

    const int tid  = threadIdx.x;
    const int bid  = blockIdx.x;
    const int b    = bid & 7;                    // batch -> XCD affine (K/V L2-resident)
    const int rest = bid >> 3;                   // 0..127
    const int stile = rest & 15;                 // 16 s-tiles x 128 rows
    const int split = rest >> 4;                 // 0..7
    const int s0 = stile * 128;
    const int w  = tid >> 6;
    const int l  = tid & 63;
    const int col = l & 15;
    const int hi4 = l >> 4;

    const int srow = s0 + 16 * w + col;
    bf16x8 q0 = *(const bf16x8*)(Q_ws + ((size_t)(b * TQ_ + srow)) * HS_ + hi4 * 8);
    bf16x8 q1 = *(const bf16x8*)(Q_ws + ((size_t)(b * TQ_ + srow)) * HS_ + hi4 * 8 + 32);

    // V base pointers per g-group (B-frag row = head h, read direct from L2)
    const unsigned short* vb0 = Vt_ws + ((size_t)(b * HS_ +  0 + col)) * TK_ + hi4 * 8;
    const unsigned short* vb1 = Vt_ws + ((size_t)(b * HS_ + 16 + col)) * TK_ + hi4 * 8;
    const unsigned short* vb2 = Vt_ws + ((size_t)(b * HS_ + 32 + col)) * TK_ + hi4 * 8;
    const unsigned short* vb3 = Vt_ws + ((size_t)(b * HS_ + 48 + col)) * TK_ + hi4 * 8;

    f32x4 oacc[4];
    #pragma unroll
    for (int g = 0; g < 4; ++g) oacc[g] = (f32x4){0.f, 0.f, 0.f, 0.f};
    f32x4 den = (f32x4){0.f, 0.f, 0.f, 0.f};

    const int tbase = split * TSPL;
    const int lin1 = tid + 512;
    const int kr_r0 = tid >> 3,  kr_h0 = (tid & 7) * 8;
    const int kr_r1 = lin1 >> 3, kr_h1 = (lin1 & 7) * 8;

    // prologue: stage K tile 0 directly
    *(uint4*)&Kt[kr_r0][kr_h0] = *(const uint4*)(K_ws + ((size_t)(b * TK_ + tbase + kr_r0)) * HS_ + kr_h0);
    *(uint4*)&Kt[kr_r1][kr_h1] = *(const uint4*)(K_ws + ((size_t)(b * TK_ + tbase + kr_r1)) * HS_ + kr_h1);
    __syncthreads();

    for (int ti = 0; ti < TSPL / 128; ++ti) {
        const int tt = tbase + ti * 128;
        const bool pre = (ti + 1 < TSPL / 128);
        uint4 kr0, kr1;
        if (pre) {   // issue next K tile's loads; they fly under QK+exp+PV
            const int tn = tt + 128;
            kr0 = *(const uint4*)(K_ws + ((size_t)(b * TK_ + tn + kr_r0)) * HS_ + kr_h0);
            kr1 = *(const uint4*)(K_ws + ((size_t)(b * TK_ + tn + kr_r1)) * HS_ + kr_h1);
        }

        // QK^T + exp + store P (bf16) into per-wave LDS; den sums f32 e
        #pragma unroll
        for (int n = 0; n < 8; ++n) {
            bf16x8 k0 = *(const bf16x8*)&Kt[n * 16 + col][hi4 * 8];
            bf16x8 k1 = *(const bf16x8*)&Kt[n * 16 + col][hi4 * 8 + 32];
            f32x4 p = (f32x4){0.f, 0.f, 0.f, 0.f};
            p = __builtin_amdgcn_mfma_f32_16x16x32_bf16(q0, k0, p, 0, 0, 0);
            p = __builtin_amdgcn_mfma_f32_16x16x32_bf16(q1, k1, p, 0, 0, 0);
            #pragma unroll
            for (int j = 0; j < 4; ++j) {
                float e = __expf(p[j]);
                den[j] += e;
                Pl[w][hi4 * 4 + j][n * 16 + col] = f2bf(e);
            }
        }
        asm volatile("s_waitcnt lgkmcnt(0)" ::: "memory");
        __builtin_amdgcn_sched_barrier(0);

        // PV: num[s][h] += P[s][t] * Vt[h][t]; V B-frag straight from L2
        #pragma unroll
        for (int c = 0; c < 4; ++c) {
            bf16x8 pa = *(const bf16x8*)&Pl[w][col][c * 32 + hi4 * 8];
            bf16x8 v0 = *(const bf16x8*)(vb0 + tt + c * 32);
            bf16x8 v1 = *(const bf16x8*)(vb1 + tt + c * 32);
            bf16x8 v2 = *(const bf16x8*)(vb2 + tt + c * 32);
            bf16x8 v3 = *(const bf16x8*)(vb3 + tt + c * 32);
            oacc[0] = __builtin_amdgcn_mfma_f32_16x16x32_bf16(pa, v0, oacc[0], 0, 0, 0);
            oacc[1] = __builtin_amdgcn_mfma_f32_16x16x32_bf16(pa, v1, oacc[1], 0, 0, 0);
            oacc[2] = __builtin_amdgcn_mfma_f32_16x16x32_bf16(pa, v2, oacc[2], 0, 0, 0);
            oacc[3] = __builtin_amdgcn_mfma_f32_16x16x32_bf16(pa, v3, oacc[3], 0, 0, 0);
        }
        __syncthreads();            // all waves done reading Kt
        if (pre) {                  // write-late: regs -> LDS
            *(uint4*)&Kt[kr_r0][kr_h0] = kr0;
            *(uint4*)&Kt[kr_r1][kr_h1] = kr1;
        }
        __syncthreads();
    }

    #pragma unroll
    for (int m = 1; m < 16; m <<= 1) {
        #pragma unroll
        for (int j = 0; j < 4; ++j) den[j] += __shfl_xor(den[j], m);
    }

    const size_t sec = (size_t)(split * B_ + b) * TQ_;
    #pragma unroll
    for (int g = 0; g < 4; ++g) {
        #pragma unroll
        for (int j = 0; j < 4; ++j) {
            int s = s0 + 16 * w + hi4 * 4 + j;
            num_ws[(sec + s) * HS_ + g * 16 + col] = oacc[g][j];
        }
    }
    if (col == 0) {
        #pragma unroll
        for (int j = 0; j < 4; ++j) {
            int s = s0 + 16 * w + hi4 * 4 + j;
            den_ws[sec + s] = den[j];
        }
    }
}

// ------------- reduce: out = sum_k num_k / sum_k den_k (NSPL=8) -------------
__global__ __launch_bounds__(256) void attn_reduce_kernel(
    const float* __restrict__ num_ws, const float* __restrict__ den_ws,
    float* __restrict__ out)
{
    const int idx = blockIdx.x * 256 + threadIdx.x;  // float4 index; 262144 total
    const int row = idx >> 4;                        // b*TQ + s
    const size_t spl4 = (size_t)B_ * TQ_ * HS_ / 4;  // split stride in float4
    const float4* n4 = (const float4*)num_ws;
    float4 a = n4[idx];
    float d = den_ws[row];
    #pragma unroll
    for (int k = 1; k < NSPL; ++k) {
        float4 v = n4[idx + (size_t)k * spl4];
        a.x += v.x; a.y += v.y; a.z += v.z; a.w += v.w;
        d += den_ws[row + k * B_ * TQ_];
    }
    float inv = 1.f / d;
    a.x *= inv; a.y *= inv; a.z *= inv; a.w *= inv;
    ((float4*)out)[idx] = a;
}

// ------------- fallback: single-pass attention (r6-verified structure) -------------
__global__ __launch_bounds__(256) void attn_kernel(
    const unsigned short* __restrict__ Q_ws,
    const unsigned short* __restrict__ K_ws,
    const unsigned short* __restrict__ Vt_ws,
    float* __restrict__ out)
{
    __shared__ unsigned short Kt[128][72];
    __shared__ unsigned short Vv[64][136];
    __shared__ unsigned short Pl[4][16][136];

    const int tid = threadIdx.x;
    const int b  = blockIdx.x & 7;
    const int s0 = (blockIdx.x >> 3) * 64;
    const int w  = tid >> 6;
    const int l  = tid & 63;
    const int col = l & 15;
    const int hi4 = l >> 4;

    const int srow = s0 + 16 * w + col;
    bf16x8 q0 = *(const bf16x8*)(Q_ws + ((size_t)(b * TQ_ + srow)) * HS_ + hi4 * 8);
    bf16x8 q1 = *(const bf16x8*)(Q_ws + ((size_t)(b * TQ_ + srow)) * HS_ + hi4 * 8 + 32);

    f32x4 oacc[4];
    #pragma unroll
    for (int g = 0; g < 4; ++g) oacc[g] = (f32x4){0.f, 0.f, 0.f, 0.f};
    f32x4 den = (f32x4){0.f, 0.f, 0.f, 0.f};

    for (int tt = 0; tt < TK_; tt += 128) {
        #pragma unroll
        for (int m = 0; m < 4; ++m) {
            int lin = tid + 256 * m;
            int r = lin >> 3;
            int h = (lin & 7) * 8;
            *(uint4*)&Kt[r][h] = *(const uint4*)(K_ws + ((size_t)(b * TK_ + tt + r)) * HS_ + h);
        }
        #pragma unroll
        for (int m = 0; m < 4; ++m) {
            int lin = tid + 256 * m;
            int h  = lin >> 4;
            int tk = (lin & 15) * 8;
            *(uint4*)&Vv[h][tk] = *(const uint4*)(Vt_ws + ((size_t)(b * HS_ + h)) * TK_ + tt + tk);
        }
        __syncthreads();

        #pragma unroll
        for (int n = 0; n < 8; ++n) {
            bf16x8 k0 = *(const bf16x8*)&Kt[n * 16 + col][hi4 * 8];
            bf16x8 k1 = *(const bf16x8*)&Kt[n * 16 + col][hi4 * 8 + 32];
            f32x4 p = (f32x4){0.f, 0.f, 0.f, 0.f};
            p = __builtin_amdgcn_mfma_f32_16x16x32_bf16(q0, k0, p, 0, 0, 0);
            p = __builtin_amdgcn_mfma_f32_16x16x32_bf16(q1, k1, p, 0, 0, 0);
            #pragma unroll
            for (int j = 0; j < 4; ++j) {
                float e = __expf(p[j]);
                den[j] += e;
                Pl[w][hi4 * 4 + j][n * 16 + col] = f2bf(e);
            }
        }
        asm volatile("s_waitcnt lgkmcnt(0)" ::: "memory");
        __builtin_amdgcn_sched_barrier(0);

        #pragma unroll
        for (int c = 0; c < 4; ++c) {
            bf16x8 pa = *(const bf16x8*)&Pl[w][col][c * 32 + hi4 * 8];
            #pragma unroll
            for (int g = 0; g < 4; ++g) {
                bf16x8 vb = *(const bf16x8*)&Vv[g * 16 + col][c * 32 + hi4 * 8];
                oacc[g] = __builtin_amdgcn_mfma_f32_16x16x32_bf16(pa, vb, oacc[g], 0, 0, 0);
            }
        }
        __syncthreads();
    }

    #pragma unroll
    for (int m = 1; m < 16; m <<= 1) {
        #pragma unroll
        for (int j = 0; j < 4; ++j) den[j] += __shfl_xor(den[j], m);
    }
    float inv[4];
    #pragma unroll
    for (int j = 0; j < 4; ++j) inv[j] = 1.f / den[j];

    #pragma unroll
    for (int g = 0; g < 4; ++g) {
        #pragma unroll
        for (int j = 0; j < 4; ++j) {
            int s = s0 + 16 * w + hi4 * 4 + j;
            out[((size_t)(b * TQ_ + s)) * HS_ + g * 16 + col] = oacc[g][j] * inv[j];
        }
    }
}

extern "C" void kernel_launch(void* const* d_in, const int* in_sizes, int n_in,
                              void* d_out, int out_size, void* d_ws, size_t ws_size,
                              hipStream_t stream) {
    const float* x_image = (const float*)d_in[0];
    const float* x_text  = (const float*)d_in[1];
    // d_in[2]: x_latex_mask — unused by the reference
    const float* fl      = (const float*)d_in[3];
    const float* fx      = (const float*)d_in[4];
    const float* fy      = (const float*)d_in[5];
    const float* Wk      = (const float*)d_in[6];
    const float* Wq      = (const float*)d_in[7];
    const float* Wv      = (const float*)d_in[8];

    unsigned short* K_ws  = (unsigned short*)d_ws;
    unsigned short* Vt_ws = K_ws + (size_t)B_ * TK_ * HS_;
    unsigned short* Q_ws  = Vt_ws + (size_t)B_ * TK_ * HS_;
    float* out = (float*)d_out;

    const size_t kvq_bytes = (size_t)(2 * B_ * TK_ * HS_ + B_ * TQ_ * HS_) * 2;  // 10 MB
    const size_t num_bytes = (size_t)NSPL * B_ * TQ_ * HS_ * 4;                  // 32 MB
    const size_t den_bytes = (size_t)NSPL * B_ * TQ_ * 4;                        // 512 KB

    proj_fused_kernel<<<dim3(768), dim3(256), 0, stream>>>(
        x_image, fx, fy, Wk, Wv, x_text, fl, Wq, K_ws, Vt_ws, Q_ws);

    if (ws_size >= kvq_bytes + num_bytes + den_bytes) {
        float* num_ws = (float*)((char*)d_ws + kvq_bytes);
        float* den_ws = num_ws + (size_t)NSPL * B_ * TQ_ * HS_;
        attn_partial_kernel<<<dim3(1024), dim3(512), 0, stream>>>(Q_ws, K_ws, Vt_ws, num_ws, den_ws);
        attn_reduce_kernel<<<dim3(B_ * TQ_ * HS_ / 4 / 256), dim3(256), 0, stream>>>(num_ws, den_ws, out);
    } else {
        attn_kernel<<<dim3(256), dim3(256), 0, stream>>>(Q_ws, K_ws, Vt_ws, out);
    }
}